// Round 10
// baseline (82.049 us; speedup 1.0000x reference)
//
#include <hip/hip_runtime.h>

#define BATCH 2
#define NTOK 256
#define DM 512
#define NH 8
#define HDIM 64
#define PD 520      // bf16 row stride for d-major (k=512) tensors
#define TSTR 264    // bf16 row stride for j-major (k=256) tensors
#define WSTR 264

typedef unsigned int uint32;
typedef unsigned short ushort16;
typedef __attribute__((ext_vector_type(8))) short bf16x8;
typedef __attribute__((ext_vector_type(4))) float f32x4;

static __device__ __forceinline__ ushort16 bf16_rne(float x) {
  uint32 u = __float_as_uint(x);
  u += 0x7fffu + ((u >> 16) & 1u);
  return (ushort16)(u >> 16);
}

// 16x32 bf16 MFMA fragment from row-major [16dim][k]: lane l -> row l&15, k-off (l>>4)*8
static __device__ __forceinline__ bf16x8 ldfrag(const ushort16* p0, int stride) {
  int l = threadIdx.x & 63;
  return *(const bf16x8*)(p0 + (size_t)(l & 15) * stride + ((l >> 4) << 3));
}

// ---------------- prep: per-token tables, 4-token register tiling ----------------
// grid 128 (= B*N/4), 512 thr (t = d). PvT/Pv2T written as uint2 (4 bf16) per row.
__global__ __launch_bounds__(512) void prep_pe(
    const float* __restrict__ coords,
    const float* __restrict__ Wb1, const float* __restrict__ bb1,
    const float* __restrict__ Wv1, const float* __restrict__ bv1,
    const float* __restrict__ Wb2, const float* __restrict__ Wv2,
    float* __restrict__ Sv, ushort16* __restrict__ SbW,
    ushort16* __restrict__ Pb, ushort16* __restrict__ PvT,
    ushort16* __restrict__ Pv2T, float* __restrict__ DjT,
    ushort16* __restrict__ Wv2b) {
  __shared__ float redD[8][8];
  int blk = blockIdx.x;            // 128 blocks: 64 per batch
  int b = blk >> 6;
  int t0 = (blk & 63) * 4;
  int d = threadIdx.x;
  int lane = d & 63, wid = d >> 6;
  float w2[NH];
#pragma unroll
  for (int h = 0; h < NH; ++h) w2[h] = Wb2[h * DM + d];
  float wb1x = Wb1[d * 3 + 0], wb1y = Wb1[d * 3 + 1], wb1z = Wb1[d * 3 + 2];
  float wv1x = Wv1[d * 3 + 0], wv1y = Wv1[d * 3 + 1], wv1z = Wv1[d * 3 + 2];
  float bb = bb1[d], bv = bv1[d];
  ushort16 pvp[4], pv2p[4];
#pragma unroll
  for (int tt = 0; tt < 4; ++tt) {
    int tok = t0 + tt, q = b * NTOK + tok;
    const float* cp = coords + q * 3;          // uniform -> s_load
    float c0 = cp[0], c1 = cp[1], c2 = cp[2];
    float pb = wb1x * c0 + wb1y * c1 + wb1z * c2;
    float pv = wv1x * c0 + wv1y * c1 + wv1z * c2;
    float sb = pb + bb;
    float sv = pv + bv;
    Sv[(size_t)q * DM + d] = sv;
    Pb[(size_t)q * PD + d] = bf16_rne(pb);
    pvp[tt] = bf16_rne(pv);
    pv2p[tt] = bf16_rne(pv * pv);
#pragma unroll
    for (int h = 0; h < NH; ++h)
      SbW[((size_t)(b * NH + h) * NTOK + tok) * PD + d] = bf16_rne(-0.5f * w2[h] * sb);
    float u = -0.5f * pb + 0.25f * pb * pb;
    float dp[NH];
#pragma unroll
    for (int h = 0; h < NH; ++h) dp[h] = w2[h] * u;
#pragma unroll
    for (int off = 32; off >= 1; off >>= 1) {
#pragma unroll
      for (int h = 0; h < NH; ++h) dp[h] += __shfl_xor(dp[h], off);
    }
    if (lane == 0) {
#pragma unroll
      for (int h = 0; h < NH; ++h) redD[wid][h] = dp[h];
    }
    __syncthreads();
    if (d < NH) {
      float s = 0.f;
#pragma unroll
      for (int w = 0; w < 8; ++w) s += redD[w][d];
      DjT[(size_t)(b * NH + d) * NTOK + tok] = s;
    }
    __syncthreads();
  }
  uint2 pk1, pk2;
  pk1.x = (uint32)pvp[0] | ((uint32)pvp[1] << 16);
  pk1.y = (uint32)pvp[2] | ((uint32)pvp[3] << 16);
  pk2.x = (uint32)pv2p[0] | ((uint32)pv2p[1] << 16);
  pk2.y = (uint32)pv2p[2] | ((uint32)pv2p[3] << 16);
  *(uint2*)&PvT [((size_t)(b * DM) + d) * TSTR + t0] = pk1;
  *(uint2*)&Pv2T[((size_t)(b * DM) + d) * TSTR + t0] = pk2;
  // Wv2 -> bf16 [row][PD]: rows blk*4 .. blk*4+3
#pragma unroll
  for (int r = 0; r < 4; ++r) {
    int row = blk * 4 + r;
    Wv2b[(size_t)row * PD + d] = bf16_rne(Wv2[(size_t)row * DM + d]);
  }
}

// ---------------- QKV projection GEMM (fp32 compute, bf16 outputs) ----------------
__global__ __launch_bounds__(256) void qkv_gemm(
    const float* __restrict__ X, const float* __restrict__ W,
    const float* __restrict__ bqkv,
    ushort16* __restrict__ Qb, ushort16* __restrict__ Kb,
    ushort16* __restrict__ VTb) {
  __shared__ float Xs[64][33];
  __shared__ float Ws[64][33];
  int t = threadIdx.x;
  int bm = blockIdx.x, bn = blockIdx.y;
  int lrow = t >> 2, lk = (t & 3) * 8;
  const float* Xp = X + (bm * 64 + lrow) * DM + lk;
  const float* Wp = W + (bn * 64 + lrow) * DM + lk;
  int tx = t & 15, ty = t >> 4;
  float acc[4][4] = {};
  for (int k0 = 0; k0 < DM; k0 += 32) {
    float4 xa = *(const float4*)(Xp + k0);
    float4 xb = *(const float4*)(Xp + k0 + 4);
    float4 wa = *(const float4*)(Wp + k0);
    float4 wb = *(const float4*)(Wp + k0 + 4);
    __syncthreads();
    Xs[lrow][lk + 0] = xa.x; Xs[lrow][lk + 1] = xa.y;
    Xs[lrow][lk + 2] = xa.z; Xs[lrow][lk + 3] = xa.w;
    Xs[lrow][lk + 4] = xb.x; Xs[lrow][lk + 5] = xb.y;
    Xs[lrow][lk + 6] = xb.z; Xs[lrow][lk + 7] = xb.w;
    Ws[lrow][lk + 0] = wa.x; Ws[lrow][lk + 1] = wa.y;
    Ws[lrow][lk + 2] = wa.z; Ws[lrow][lk + 3] = wa.w;
    Ws[lrow][lk + 4] = wb.x; Ws[lrow][lk + 5] = wb.y;
    Ws[lrow][lk + 6] = wb.z; Ws[lrow][lk + 7] = wb.w;
    __syncthreads();
#pragma unroll
    for (int kk = 0; kk < 32; ++kk) {
      float a0 = Xs[ty * 4 + 0][kk], a1 = Xs[ty * 4 + 1][kk];
      float a2 = Xs[ty * 4 + 2][kk], a3 = Xs[ty * 4 + 3][kk];
      float b0 = Ws[tx * 4 + 0][kk], b1 = Ws[tx * 4 + 1][kk];
      float b2 = Ws[tx * 4 + 2][kk], b3 = Ws[tx * 4 + 3][kk];
      acc[0][0] = fmaf(a0, b0, acc[0][0]); acc[0][1] = fmaf(a0, b1, acc[0][1]);
      acc[0][2] = fmaf(a0, b2, acc[0][2]); acc[0][3] = fmaf(a0, b3, acc[0][3]);
      acc[1][0] = fmaf(a1, b0, acc[1][0]); acc[1][1] = fmaf(a1, b1, acc[1][1]);
      acc[1][2] = fmaf(a1, b2, acc[1][2]); acc[1][3] = fmaf(a1, b3, acc[1][3]);
      acc[2][0] = fmaf(a2, b0, acc[2][0]); acc[2][1] = fmaf(a2, b1, acc[2][1]);
      acc[2][2] = fmaf(a2, b2, acc[2][2]); acc[2][3] = fmaf(a2, b3, acc[2][3]);
      acc[3][0] = fmaf(a3, b0, acc[3][0]); acc[3][1] = fmaf(a3, b1, acc[3][1]);
      acc[3][2] = fmaf(a3, b2, acc[3][2]); acc[3][3] = fmaf(a3, b3, acc[3][3]);
    }
  }
#pragma unroll
  for (int r = 0; r < 4; ++r) {
    int row = bm * 64 + ty * 4 + r;
    int b = row >> 8, i = row & (NTOK - 1);
#pragma unroll
    for (int c = 0; c < 4; ++c) {
      int n = bn * 64 + tx * 4 + c;
      float val = acc[r][c] + bqkv[n];
      if (n < DM) {
        int h = n >> 6, dp = n & 63;
        Qb[((size_t)(b * NH + h) * NTOK + i) * HDIM + dp] = bf16_rne(val * 0.125f);
      } else if (n < 2 * DM) {
        int u = n - DM; int h = u >> 6, dp = u & 63;
        Kb[((size_t)(b * NH + h) * NTOK + i) * HDIM + dp] = bf16_rne(val);
      } else {
        int u = n - 2 * DM; int h = u >> 6, dp = u & 63;
        VTb[((size_t)(b * NH + h) * HDIM + dp) * TSTR + i] = bf16_rne(val);
      }
    }
  }
}

// ---------------- attn_fused: scores -> softmax (LDS) -> P1/P2 -> Taylor g -> out ----
// 1-D grid 256 (XCD-chunked: XCD k owns bh {2k,2k+1}), 256 thr = 4 waves.
// Score: wave w = 64-j strip.  Phase A: wave w = 128-d strip.  Phase B: wave w = 16-o strip.
__global__ __launch_bounds__(256) void attn_fused(
    const ushort16* __restrict__ Qb, const ushort16* __restrict__ Kb,
    const ushort16* __restrict__ SbW, const ushort16* __restrict__ Pb,
    const float* __restrict__ DjT,
    const ushort16* __restrict__ PvT, const ushort16* __restrict__ Pv2T,
    const float* __restrict__ Sv,
    const ushort16* __restrict__ Wv2b, const ushort16* __restrict__ VTb,
    const float* __restrict__ bv2, float* __restrict__ out) {
  __shared__ ushort16 wsh[16][WSTR];     // softmax weights bf16 (8.4 KB)
  __shared__ ushort16 gsh[16][DM + 8];   // g bf16 (16.6 KB)
  __shared__ float redm[4][16];
  __shared__ float reds[4][16];
  int t = threadIdx.x;
  int w = t >> 6, lane = t & 63;
  int wid = ((blockIdx.x & 7) << 5) + (blockIdx.x >> 3);   // XCD-chunked work id
  int bh = wid >> 4;
  int b = bh >> 3, h = bh & 7;
  int ib = (wid & 15) << 4;
  int col = lane & 15, rb = (lane >> 4) * 4;
  int j0 = w * 64;

  // ---- scores: qk (K=64) + C-term (K=512) ----
  f32x4 acc[4] = {};
  {
    const ushort16* qbase = Qb + ((size_t)bh * NTOK + ib) * HDIM;
    const ushort16* kbase = Kb + ((size_t)bh * NTOK + j0) * HDIM;
#pragma unroll
    for (int kb = 0; kb < 2; ++kb) {
      bf16x8 af = ldfrag(qbase + kb * 32, HDIM);
#pragma unroll
      for (int jf = 0; jf < 4; ++jf) {
        bf16x8 bf = ldfrag(kbase + (size_t)jf * 16 * HDIM + kb * 32, HDIM);
        acc[jf] = __builtin_amdgcn_mfma_f32_16x16x32_bf16(af, bf, acc[jf], 0, 0, 0);
      }
    }
  }
  {
    const ushort16* abase = SbW + ((size_t)bh * NTOK + ib) * PD;
    const ushort16* bbase = Pb + ((size_t)(b * NTOK) + j0) * PD;
#pragma unroll 4
    for (int kb = 0; kb < 16; ++kb) {
      bf16x8 af = ldfrag(abase + kb * 32, PD);
#pragma unroll
      for (int jf = 0; jf < 4; ++jf) {
        bf16x8 bf = ldfrag(bbase + (size_t)jf * 16 * PD + kb * 32, PD);
        acc[jf] = __builtin_amdgcn_mfma_f32_16x16x32_bf16(af, bf, acc[jf], 0, 0, 0);
      }
    }
  }
  // ---- + Dj, softmax over j ----
  float sc[4][4];
#pragma unroll
  for (int jf = 0; jf < 4; ++jf) {
    float dj = DjT[(size_t)bh * NTOK + j0 + jf * 16 + col];
#pragma unroll
    for (int r = 0; r < 4; ++r) sc[jf][r] = acc[jf][r] + dj;
  }
#pragma unroll
  for (int r = 0; r < 4; ++r) {
    float m = fmaxf(fmaxf(sc[0][r], sc[1][r]), fmaxf(sc[2][r], sc[3][r]));
    m = fmaxf(m, __shfl_xor(m, 1));
    m = fmaxf(m, __shfl_xor(m, 2));
    m = fmaxf(m, __shfl_xor(m, 4));
    m = fmaxf(m, __shfl_xor(m, 8));
    if (col == 0) redm[w][rb + r] = m;
  }
  __syncthreads();
  float mrow[4];
#pragma unroll
  for (int r = 0; r < 4; ++r)
    mrow[r] = fmaxf(fmaxf(redm[0][rb + r], redm[1][rb + r]),
                    fmaxf(redm[2][rb + r], redm[3][rb + r]));
#pragma unroll
  for (int r = 0; r < 4; ++r) {
    float su = 0.f;
#pragma unroll
    for (int jf = 0; jf < 4; ++jf) {
      float e = __expf(sc[jf][r] - mrow[r]);
      sc[jf][r] = e;
      su += e;
    }
    su += __shfl_xor(su, 1);
    su += __shfl_xor(su, 2);
    su += __shfl_xor(su, 4);
    su += __shfl_xor(su, 8);
    if (col == 0) reds[w][rb + r] = su;
  }
  __syncthreads();
#pragma unroll
  for (int r = 0; r < 4; ++r) {
    float stot = (reds[0][rb + r] + reds[1][rb + r]) + (reds[2][rb + r] + reds[3][rb + r]);
    float inv = __builtin_amdgcn_rcpf(stot);
#pragma unroll
    for (int jf = 0; jf < 4; ++jf)
      wsh[rb + r][j0 + jf * 16 + col] = bf16_rne(sc[jf][r] * inv);
  }
  __syncthreads();

  // ---- phase A: P1/P2 for d0 = w*128, K=256, A from LDS ----
  int d0 = w * 128;
  f32x4 a1[8] = {}, a2[8] = {};
  {
    const ushort16* b1 = PvT + ((size_t)(b * DM) + d0) * TSTR;
    const ushort16* b2 = Pv2T + ((size_t)(b * DM) + d0) * TSTR;
#pragma unroll 2
    for (int kb = 0; kb < 8; ++kb) {
      bf16x8 af = *(const bf16x8*)&wsh[lane & 15][kb * 32 + ((lane >> 4) << 3)];
#pragma unroll
      for (int df = 0; df < 8; ++df) {
        bf16x8 f1 = ldfrag(b1 + (size_t)df * 16 * TSTR + kb * 32, TSTR);
        a1[df] = __builtin_amdgcn_mfma_f32_16x16x32_bf16(af, f1, a1[df], 0, 0, 0);
        bf16x8 f2 = ldfrag(b2 + (size_t)df * 16 * TSTR + kb * 32, TSTR);
        a2[df] = __builtin_amdgcn_mfma_f32_16x16x32_bf16(af, f2, a2[df], 0, 0, 0);
      }
    }
  }
  // Taylor epilogue -> g (bf16) into LDS
#pragma unroll
  for (int df = 0; df < 8; ++df) {
#pragma unroll
    for (int r = 0; r < 4; ++r) {
      int ig = ib + rb + r;
      int dg = d0 + df * 16 + col;
      float sv = Sv[((size_t)(b * NTOK) + ig) * DM + dg];
      float p1 = a1[df][r], p2 = a2[df][r];
      float g = 0.5f * (sv - p1) + 0.25f * (sv * sv - 2.f * sv * p1 + p2);
      gsh[rb + r][dg] = bf16_rne(g);
    }
  }
  __syncthreads();

  // ---- phase B: out strip o0 = w*16 ----
  f32x4 acc2 = {};
  {  // g @ Wv2_h^T, K=512, A from LDS
    const ushort16* wvb = Wv2b + (size_t)(h * HDIM + w * 16) * PD;
#pragma unroll 4
    for (int kb = 0; kb < 16; ++kb) {
      bf16x8 af = *(const bf16x8*)&gsh[lane & 15][kb * 32 + ((lane >> 4) << 3)];
      bf16x8 bf = ldfrag(wvb + kb * 32, PD);
      acc2 = __builtin_amdgcn_mfma_f32_16x16x32_bf16(af, bf, acc2, 0, 0, 0);
    }
  }
  {  // Wsm @ V, K=256, A from LDS
    const ushort16* vtb = VTb + (size_t)(bh * HDIM + w * 16) * TSTR;
#pragma unroll 2
    for (int kb = 0; kb < 8; ++kb) {
      bf16x8 af = *(const bf16x8*)&wsh[lane & 15][kb * 32 + ((lane >> 4) << 3)];
      bf16x8 bf = ldfrag(vtb + kb * 32, TSTR);
      acc2 = __builtin_amdgcn_mfma_f32_16x16x32_bf16(af, bf, acc2, 0, 0, 0);
    }
  }
#pragma unroll
  for (int r = 0; r < 4; ++r) {
    int ig = ib + rb + r;
    int o = h * HDIM + w * 16 + col;
    out[((size_t)(b * NTOK) + ig) * DM + o] = acc2[r] + bv2[o];
  }
}

extern "C" void kernel_launch(void* const* d_in, const int* in_sizes, int n_in,
                              void* d_out, int out_size, void* d_ws, size_t ws_size,
                              hipStream_t stream) {
  const float* x      = (const float*)d_in[0];
  const float* coords = (const float*)d_in[1];
  const float* Wqkv   = (const float*)d_in[2];
  const float* bqkv   = (const float*)d_in[3];
  const float* Wb1    = (const float*)d_in[4];
  const float* bb1    = (const float*)d_in[5];
  const float* Wb2    = (const float*)d_in[6];
  // d_in[7] = bb2: softmax-invariant, unused
  const float* Wv1    = (const float*)d_in[8];
  const float* bv1    = (const float*)d_in[9];
  const float* Wv2    = (const float*)d_in[10];
  const float* bv2    = (const float*)d_in[11];
  float* outp = (float*)d_out;
  float* ws = (float*)d_ws;

  const size_t SZ = (size_t)BATCH * NTOK * DM;           // 262144
  float* Svw = ws;
  float* DjT = ws + SZ;                                  // [bh][j], 4096 floats
  ushort16* SbW  = (ushort16*)(DjT + 4096);              // [bh][tok][PD]
  ushort16* Pbw  = SbW + (size_t)BATCH * NH * NTOK * PD;
  ushort16* PvT  = Pbw + (size_t)BATCH * NTOK * PD;      // [b][d][TSTR]
  ushort16* Pv2T = PvT + (size_t)BATCH * DM * TSTR;
  ushort16* Qb   = Pv2T + (size_t)BATCH * DM * TSTR;     // [bh][i][64]
  ushort16* Kb   = Qb + (size_t)BATCH * NH * NTOK * HDIM;
  ushort16* VTb  = Kb + (size_t)BATCH * NH * NTOK * HDIM;    // [bh][dp][TSTR]
  ushort16* Wv2b = VTb + (size_t)BATCH * NH * HDIM * TSTR;   // [o][PD]

  hipLaunchKernelGGL(prep_pe, dim3(BATCH * NTOK / 4), dim3(512), 0, stream,
                     coords, Wb1, bb1, Wv1, bv1, Wb2, Wv2,
                     Svw, SbW, Pbw, PvT, Pv2T, DjT, Wv2b);
  hipLaunchKernelGGL(qkv_gemm, dim3(8, 24), dim3(256), 0, stream,
                     x, Wqkv, bqkv, Qb, Kb, VTb);
  hipLaunchKernelGGL(attn_fused, dim3(BATCH * NH * 16), dim3(256), 0, stream,
                     Qb, Kb, SbW, Pbw, DjT, PvT, Pv2T, Svw, Wv2b, VTb, bv2, outp);
}

// Round 11
// 67.048 us; speedup vs baseline: 1.2237x; 1.2237x over previous
//
#include <hip/hip_runtime.h>

#define BATCH 2
#define NTOK 256
#define DM 512
#define NH 8
#define HDIM 64
#define PD 520      // bf16 row stride for d-major (k=512) tensors
#define TSTR 264    // bf16 row stride for j-major (k=256) tensors
#define WSTR 264

typedef unsigned int uint32;
typedef unsigned short ushort16;
typedef __attribute__((ext_vector_type(8))) short bf16x8;
typedef __attribute__((ext_vector_type(4))) float f32x4;

static __device__ __forceinline__ ushort16 bf16_rne(float x) {
  uint32 u = __float_as_uint(x);
  u += 0x7fffu + ((u >> 16) & 1u);
  return (ushort16)(u >> 16);
}

// 16x32 bf16 MFMA fragment from row-major [16dim][k]: lane l -> row l&15, k-off (l>>4)*8
static __device__ __forceinline__ bf16x8 ldfrag(const ushort16* p0, int stride) {
  int l = threadIdx.x & 63;
  return *(const bf16x8*)(p0 + (size_t)(l & 15) * stride + ((l >> 4) << 3));
}

// ---------------- prep_qkv: horizontal fusion of QKV GEMM (blocks 0-191) ----------
// ---------------- and pair-table prep (blocks 192-319) -----------------------------
__global__ __launch_bounds__(256) void prep_qkv(
    // qkv args
    const float* __restrict__ X, const float* __restrict__ W,
    const float* __restrict__ bqkv,
    ushort16* __restrict__ Qb, ushort16* __restrict__ Kb,
    ushort16* __restrict__ VTb,
    // prep args
    const float* __restrict__ coords,
    const float* __restrict__ Wb1, const float* __restrict__ bb1,
    const float* __restrict__ Wv1, const float* __restrict__ bv1,
    const float* __restrict__ Wb2, const float* __restrict__ Wv2,
    float* __restrict__ Sv, ushort16* __restrict__ SbW,
    ushort16* __restrict__ Pb, ushort16* __restrict__ PvT,
    ushort16* __restrict__ Pv2T, float* __restrict__ DjT,
    ushort16* __restrict__ Wv2b) {
  __shared__ float Xs[64][33];
  __shared__ float Ws[64][33];
  __shared__ float redD[4][8];
  int t = threadIdx.x;

  if (blockIdx.x < 192) {
    // ================= QKV GEMM path =================
    int bm = blockIdx.x & 7, bn = blockIdx.x >> 3;
    int lrow = t >> 2, lk = (t & 3) * 8;
    const float* Xp = X + (bm * 64 + lrow) * DM + lk;
    const float* Wp = W + (bn * 64 + lrow) * DM + lk;
    int tx = t & 15, ty = t >> 4;
    float acc[4][4] = {};
    for (int k0 = 0; k0 < DM; k0 += 32) {
      float4 xa = *(const float4*)(Xp + k0);
      float4 xb = *(const float4*)(Xp + k0 + 4);
      float4 wa = *(const float4*)(Wp + k0);
      float4 wb = *(const float4*)(Wp + k0 + 4);
      __syncthreads();
      Xs[lrow][lk + 0] = xa.x; Xs[lrow][lk + 1] = xa.y;
      Xs[lrow][lk + 2] = xa.z; Xs[lrow][lk + 3] = xa.w;
      Xs[lrow][lk + 4] = xb.x; Xs[lrow][lk + 5] = xb.y;
      Xs[lrow][lk + 6] = xb.z; Xs[lrow][lk + 7] = xb.w;
      Ws[lrow][lk + 0] = wa.x; Ws[lrow][lk + 1] = wa.y;
      Ws[lrow][lk + 2] = wa.z; Ws[lrow][lk + 3] = wa.w;
      Ws[lrow][lk + 4] = wb.x; Ws[lrow][lk + 5] = wb.y;
      Ws[lrow][lk + 6] = wb.z; Ws[lrow][lk + 7] = wb.w;
      __syncthreads();
#pragma unroll
      for (int kk = 0; kk < 32; ++kk) {
        float a0 = Xs[ty * 4 + 0][kk], a1 = Xs[ty * 4 + 1][kk];
        float a2 = Xs[ty * 4 + 2][kk], a3 = Xs[ty * 4 + 3][kk];
        float b0 = Ws[tx * 4 + 0][kk], b1 = Ws[tx * 4 + 1][kk];
        float b2 = Ws[tx * 4 + 2][kk], b3 = Ws[tx * 4 + 3][kk];
        acc[0][0] = fmaf(a0, b0, acc[0][0]); acc[0][1] = fmaf(a0, b1, acc[0][1]);
        acc[0][2] = fmaf(a0, b2, acc[0][2]); acc[0][3] = fmaf(a0, b3, acc[0][3]);
        acc[1][0] = fmaf(a1, b0, acc[1][0]); acc[1][1] = fmaf(a1, b1, acc[1][1]);
        acc[1][2] = fmaf(a1, b2, acc[1][2]); acc[1][3] = fmaf(a1, b3, acc[1][3]);
        acc[2][0] = fmaf(a2, b0, acc[2][0]); acc[2][1] = fmaf(a2, b1, acc[2][1]);
        acc[2][2] = fmaf(a2, b2, acc[2][2]); acc[2][3] = fmaf(a2, b3, acc[2][3]);
        acc[3][0] = fmaf(a3, b0, acc[3][0]); acc[3][1] = fmaf(a3, b1, acc[3][1]);
        acc[3][2] = fmaf(a3, b2, acc[3][2]); acc[3][3] = fmaf(a3, b3, acc[3][3]);
      }
    }
#pragma unroll
    for (int r = 0; r < 4; ++r) {
      int row = bm * 64 + ty * 4 + r;
      int b = row >> 8, i = row & (NTOK - 1);
#pragma unroll
      for (int c = 0; c < 4; ++c) {
        int n = bn * 64 + tx * 4 + c;
        float val = acc[r][c] + bqkv[n];
        if (n < DM) {
          int h = n >> 6, dp = n & 63;
          Qb[((size_t)(b * NH + h) * NTOK + i) * HDIM + dp] = bf16_rne(val * 0.125f);
        } else if (n < 2 * DM) {
          int u = n - DM; int h = u >> 6, dp = u & 63;
          Kb[((size_t)(b * NH + h) * NTOK + i) * HDIM + dp] = bf16_rne(val);
        } else {
          int u = n - 2 * DM; int h = u >> 6, dp = u & 63;
          VTb[((size_t)(b * NH + h) * HDIM + dp) * TSTR + i] = bf16_rne(val);
        }
      }
    }
  } else {
    // ================= prep path: 4 tokens, 2 d per thread =================
    int blk = blockIdx.x - 192;      // 128 blocks: 64 per batch
    int b = blk >> 6;
    int t0 = (blk & 63) * 4;
    int lane = t & 63, wv = t >> 6;
    float w2a[NH], w2b[NH];
#pragma unroll
    for (int h = 0; h < NH; ++h) {
      w2a[h] = Wb2[h * DM + t];
      w2b[h] = Wb2[h * DM + t + 256];
    }
    float b1ax = Wb1[t * 3 + 0], b1ay = Wb1[t * 3 + 1], b1az = Wb1[t * 3 + 2];
    float b1bx = Wb1[(t + 256) * 3 + 0], b1by = Wb1[(t + 256) * 3 + 1], b1bz = Wb1[(t + 256) * 3 + 2];
    float v1ax = Wv1[t * 3 + 0], v1ay = Wv1[t * 3 + 1], v1az = Wv1[t * 3 + 2];
    float v1bx = Wv1[(t + 256) * 3 + 0], v1by = Wv1[(t + 256) * 3 + 1], v1bz = Wv1[(t + 256) * 3 + 2];
    float bba = bb1[t], bbb = bb1[t + 256];
    float bva = bv1[t], bvb = bv1[t + 256];
    ushort16 pvp[2][4], pv2p[2][4];
#pragma unroll
    for (int tt = 0; tt < 4; ++tt) {
      int tok = t0 + tt, q = b * NTOK + tok;
      const float* cp = coords + q * 3;        // uniform -> s_load
      float c0 = cp[0], c1 = cp[1], c2 = cp[2];
      float pba = b1ax * c0 + b1ay * c1 + b1az * c2;
      float pbb = b1bx * c0 + b1by * c1 + b1bz * c2;
      float pva = v1ax * c0 + v1ay * c1 + v1az * c2;
      float pvb = v1bx * c0 + v1by * c1 + v1bz * c2;
      float sba = pba + bba, sbb = pbb + bbb;
      Sv[(size_t)q * DM + t] = pva + bva;
      Sv[(size_t)q * DM + t + 256] = pvb + bvb;
      Pb[(size_t)q * PD + t] = bf16_rne(pba);
      Pb[(size_t)q * PD + t + 256] = bf16_rne(pbb);
      pvp[0][tt] = bf16_rne(pva);
      pvp[1][tt] = bf16_rne(pvb);
      pv2p[0][tt] = bf16_rne(pva * pva);
      pv2p[1][tt] = bf16_rne(pvb * pvb);
#pragma unroll
      for (int h = 0; h < NH; ++h) {
        size_t base = ((size_t)(b * NH + h) * NTOK + tok) * PD;
        SbW[base + t] = bf16_rne(-0.5f * w2a[h] * sba);
        SbW[base + t + 256] = bf16_rne(-0.5f * w2b[h] * sbb);
      }
      float ua = -0.5f * pba + 0.25f * pba * pba;
      float ub = -0.5f * pbb + 0.25f * pbb * pbb;
      float dp[NH];
#pragma unroll
      for (int h = 0; h < NH; ++h) dp[h] = fmaf(w2a[h], ua, w2b[h] * ub);
#pragma unroll
      for (int off = 32; off >= 1; off >>= 1) {
#pragma unroll
        for (int h = 0; h < NH; ++h) dp[h] += __shfl_xor(dp[h], off);
      }
      if (lane == 0) {
#pragma unroll
        for (int h = 0; h < NH; ++h) redD[wv][h] = dp[h];
      }
      __syncthreads();
      if (t < NH) {
        float s = (redD[0][t] + redD[1][t]) + (redD[2][t] + redD[3][t]);
        DjT[(size_t)(b * NH + t) * NTOK + tok] = s;
      }
      __syncthreads();
    }
    uint2 k1, k2;
#pragma unroll
    for (int hh = 0; hh < 2; ++hh) {
      int d = t + hh * 256;
      k1.x = (uint32)pvp[hh][0] | ((uint32)pvp[hh][1] << 16);
      k1.y = (uint32)pvp[hh][2] | ((uint32)pvp[hh][3] << 16);
      k2.x = (uint32)pv2p[hh][0] | ((uint32)pv2p[hh][1] << 16);
      k2.y = (uint32)pv2p[hh][2] | ((uint32)pv2p[hh][3] << 16);
      *(uint2*)&PvT [((size_t)(b * DM) + d) * TSTR + t0] = k1;
      *(uint2*)&Pv2T[((size_t)(b * DM) + d) * TSTR + t0] = k2;
    }
    // Wv2 -> bf16 [row][PD]: rows blk*4 .. blk*4+3
#pragma unroll
    for (int r = 0; r < 4; ++r) {
      int row = blk * 4 + r;
      Wv2b[(size_t)row * PD + t] = bf16_rne(Wv2[(size_t)row * DM + t]);
      Wv2b[(size_t)row * PD + t + 256] = bf16_rne(Wv2[(size_t)row * DM + t + 256]);
    }
  }
}

// ---------------- score_softmax (MFMA + fused softmax), 8 waves ----------------
// grid (16 i-tiles, 16 bh), 512 thr. Wave w: 16i x 32j strip (j0 = w*32).
__global__ __launch_bounds__(512) void score_softmax(
    const ushort16* __restrict__ Qb, const ushort16* __restrict__ Kb,
    const ushort16* __restrict__ SbW, const ushort16* __restrict__ Pb,
    const float* __restrict__ DjT, ushort16* __restrict__ Wsmb) {
  __shared__ float redm[8][16];
  __shared__ float reds[8][16];
  int t = threadIdx.x;
  int w = t >> 6, lane = t & 63;
  int bh = blockIdx.y;
  int b = bh >> 3;
  int ib = blockIdx.x * 16;
  int j0 = w * 32;
  int col = lane & 15, rb = (lane >> 4) * 4;
  f32x4 acc[2] = {};
  {  // qk over K=64
    const ushort16* qbase = Qb + ((size_t)bh * NTOK + ib) * HDIM;
    const ushort16* kbase = Kb + ((size_t)bh * NTOK + j0) * HDIM;
#pragma unroll
    for (int kb = 0; kb < 2; ++kb) {
      bf16x8 af = ldfrag(qbase + kb * 32, HDIM);
#pragma unroll
      for (int jf = 0; jf < 2; ++jf) {
        bf16x8 bf = ldfrag(kbase + (size_t)jf * 16 * HDIM + kb * 32, HDIM);
        acc[jf] = __builtin_amdgcn_mfma_f32_16x16x32_bf16(af, bf, acc[jf], 0, 0, 0);
      }
    }
  }
  {  // C-term over K=512 (-0.5 folded into SbW)
    const ushort16* abase = SbW + ((size_t)bh * NTOK + ib) * PD;
    const ushort16* bbase = Pb + ((size_t)(b * NTOK) + j0) * PD;
#pragma unroll 4
    for (int kb = 0; kb < 16; ++kb) {
      bf16x8 af = ldfrag(abase + kb * 32, PD);
#pragma unroll
      for (int jf = 0; jf < 2; ++jf) {
        bf16x8 bf = ldfrag(bbase + (size_t)jf * 16 * PD + kb * 32, PD);
        acc[jf] = __builtin_amdgcn_mfma_f32_16x16x32_bf16(af, bf, acc[jf], 0, 0, 0);
      }
    }
  }
  // scores = acc + Dj
  float sc[2][4];
#pragma unroll
  for (int jf = 0; jf < 2; ++jf) {
    float dj = DjT[(size_t)bh * NTOK + j0 + jf * 16 + col];
#pragma unroll
    for (int r = 0; r < 4; ++r) sc[jf][r] = acc[jf][r] + dj;
  }
#pragma unroll
  for (int r = 0; r < 4; ++r) {
    float m = fmaxf(sc[0][r], sc[1][r]);
    m = fmaxf(m, __shfl_xor(m, 1));
    m = fmaxf(m, __shfl_xor(m, 2));
    m = fmaxf(m, __shfl_xor(m, 4));
    m = fmaxf(m, __shfl_xor(m, 8));
    if (col == 0) redm[w][rb + r] = m;
  }
  __syncthreads();
  float mrow[4];
#pragma unroll
  for (int r = 0; r < 4; ++r) {
    float m = redm[0][rb + r];
#pragma unroll
    for (int ww = 1; ww < 8; ++ww) m = fmaxf(m, redm[ww][rb + r]);
    mrow[r] = m;
  }
#pragma unroll
  for (int r = 0; r < 4; ++r) {
    float su = 0.f;
#pragma unroll
    for (int jf = 0; jf < 2; ++jf) {
      float e = __expf(sc[jf][r] - mrow[r]);
      sc[jf][r] = e;
      su += e;
    }
    su += __shfl_xor(su, 1);
    su += __shfl_xor(su, 2);
    su += __shfl_xor(su, 4);
    su += __shfl_xor(su, 8);
    if (col == 0) reds[w][rb + r] = su;
  }
  __syncthreads();
#pragma unroll
  for (int r = 0; r < 4; ++r) {
    float stot = 0.f;
#pragma unroll
    for (int ww = 0; ww < 8; ++ww) stot += reds[ww][rb + r];
    float inv = __builtin_amdgcn_rcpf(stot);
    int row = ib + rb + r;
#pragma unroll
    for (int jf = 0; jf < 2; ++jf)
      Wsmb[((size_t)bh * NTOK + row) * WSTR + j0 + jf * 16 + col] = bf16_rne(sc[jf][r] * inv);
  }
}

// ---------------- pv_out (MFMA), 8 waves ----------------
// Phase A: wave w -> P1/P2 for 16i x 64d (d0=w*64), K=256; Taylor g -> LDS bf16.
// Phase B: waves 0-3 -> g@Wv2^T (K=512) o-strip w*16 into LDS float;
//          waves 4-7 -> Wsm@V (K=256) o-strip (w-4)*16; combine + bv2 -> out.
__global__ __launch_bounds__(512) void pv_out(
    const ushort16* __restrict__ Wsmb, const ushort16* __restrict__ PvT,
    const ushort16* __restrict__ Pv2T, const float* __restrict__ Sv,
    const ushort16* __restrict__ Wv2b, const ushort16* __restrict__ VTb,
    const float* __restrict__ bv2, float* __restrict__ out) {
  __shared__ ushort16 gsh[16][DM + 8];   // 16.6 KB
  __shared__ float fB[16][68];           // 4.3 KB
  int t = threadIdx.x;
  int w = t >> 6, lane = t & 63;
  int bh = blockIdx.y;
  int b = bh >> 3, h = bh & 7;
  int ib = blockIdx.x * 16;
  int col = lane & 15, rb = (lane >> 4) * 4;
  const ushort16* abase = Wsmb + ((size_t)bh * NTOK + ib) * WSTR;

  // ---- phase A ----
  int d0 = w * 64;
  f32x4 a1[4] = {}, a2[4] = {};
  {
    const ushort16* b1 = PvT + ((size_t)(b * DM) + d0) * TSTR;
    const ushort16* b2 = Pv2T + ((size_t)(b * DM) + d0) * TSTR;
#pragma unroll 2
    for (int kb = 0; kb < 8; ++kb) {
      bf16x8 af = ldfrag(abase + kb * 32, WSTR);
#pragma unroll
      for (int df = 0; df < 4; ++df) {
        bf16x8 f1 = ldfrag(b1 + (size_t)df * 16 * TSTR + kb * 32, TSTR);
        a1[df] = __builtin_amdgcn_mfma_f32_16x16x32_bf16(af, f1, a1[df], 0, 0, 0);
        bf16x8 f2 = ldfrag(b2 + (size_t)df * 16 * TSTR + kb * 32, TSTR);
        a2[df] = __builtin_amdgcn_mfma_f32_16x16x32_bf16(af, f2, a2[df], 0, 0, 0);
      }
    }
  }
#pragma unroll
  for (int df = 0; df < 4; ++df) {
#pragma unroll
    for (int r = 0; r < 4; ++r) {
      int ig = ib + rb + r;
      int dg = d0 + df * 16 + col;
      float sv = Sv[((size_t)(b * NTOK) + ig) * DM + dg];
      float p1 = a1[df][r], p2 = a2[df][r];
      float g = 0.5f * (sv - p1) + 0.25f * (sv * sv - 2.f * sv * p1 + p2);
      gsh[rb + r][dg] = bf16_rne(g);
    }
  }
  __syncthreads();

  // ---- phase B (split K-work across wave halves) ----
  f32x4 acc2 = {};
  if (w < 4) {  // g @ Wv2_h^T, K=512, A from LDS
    const ushort16* wvb = Wv2b + (size_t)(h * HDIM + w * 16) * PD;
#pragma unroll 4
    for (int kb = 0; kb < 16; ++kb) {
      bf16x8 af = *(const bf16x8*)&gsh[col][kb * 32 + ((lane >> 4) << 3)];
      bf16x8 bf = ldfrag(wvb + kb * 32, PD);
      acc2 = __builtin_amdgcn_mfma_f32_16x16x32_bf16(af, bf, acc2, 0, 0, 0);
    }
  } else {      // Wsm @ V, K=256
    const ushort16* vtb = VTb + (size_t)(bh * HDIM + (w - 4) * 16) * TSTR;
#pragma unroll 2
    for (int kb = 0; kb < 8; ++kb) {
      bf16x8 af = ldfrag(abase + kb * 32, WSTR);
      bf16x8 bf = ldfrag(vtb + kb * 32, TSTR);
      acc2 = __builtin_amdgcn_mfma_f32_16x16x32_bf16(af, bf, acc2, 0, 0, 0);
    }
  }
  if (w < 4) {
#pragma unroll
    for (int r = 0; r < 4; ++r) fB[rb + r][w * 16 + col] = acc2[r];
  }
  __syncthreads();
  if (w >= 4) {
    int o = h * HDIM + (w - 4) * 16 + col;
    float bv = bv2[o];
#pragma unroll
    for (int r = 0; r < 4; ++r) {
      int ig = ib + rb + r;
      out[((size_t)(b * NTOK) + ig) * DM + o] = fB[rb + r][(w - 4) * 16 + col] + acc2[r] + bv;
    }
  }
}

extern "C" void kernel_launch(void* const* d_in, const int* in_sizes, int n_in,
                              void* d_out, int out_size, void* d_ws, size_t ws_size,
                              hipStream_t stream) {
  const float* x      = (const float*)d_in[0];
  const float* coords = (const float*)d_in[1];
  const float* Wqkv   = (const float*)d_in[2];
  const float* bqkv   = (const float*)d_in[3];
  const float* Wb1    = (const float*)d_in[4];
  const float* bb1    = (const float*)d_in[5];
  const float* Wb2    = (const float*)d_in[6];
  // d_in[7] = bb2: softmax-invariant, unused
  const float* Wv1    = (const float*)d_in[8];
  const float* bv1    = (const float*)d_in[9];
  const float* Wv2    = (const float*)d_in[10];
  const float* bv2    = (const float*)d_in[11];
  float* outp = (float*)d_out;
  float* ws = (float*)d_ws;

  const size_t SZ = (size_t)BATCH * NTOK * DM;           // 262144
  float* Svw = ws;
  float* DjT = ws + SZ;                                  // [bh][j], 4096 floats
  ushort16* SbW  = (ushort16*)(DjT + 4096);              // [bh][tok][PD]
  ushort16* Pbw  = SbW + (size_t)BATCH * NH * NTOK * PD;
  ushort16* PvT  = Pbw + (size_t)BATCH * NTOK * PD;      // [b][d][TSTR]
  ushort16* Pv2T = PvT + (size_t)BATCH * DM * TSTR;
  ushort16* Wsmb = Pv2T + (size_t)BATCH * DM * TSTR;     // [bh][i][WSTR]
  ushort16* Qb   = Wsmb + (size_t)BATCH * NH * NTOK * WSTR;  // [bh][i][64]
  ushort16* Kb   = Qb + (size_t)BATCH * NH * NTOK * HDIM;
  ushort16* VTb  = Kb + (size_t)BATCH * NH * NTOK * HDIM;    // [bh][dp][TSTR]
  ushort16* Wv2b = VTb + (size_t)BATCH * NH * HDIM * TSTR;   // [o][PD]

  hipLaunchKernelGGL(prep_qkv, dim3(320), dim3(256), 0, stream,
                     x, Wqkv, bqkv, Qb, Kb, VTb,
                     coords, Wb1, bb1, Wv1, bv1, Wb2, Wv2,
                     Svw, SbW, Pbw, PvT, Pv2T, DjT, Wv2b);
  hipLaunchKernelGGL(score_softmax, dim3(16, BATCH * NH), dim3(512), 0, stream,
                     Qb, Kb, SbW, Pbw, DjT, Wsmb);
  hipLaunchKernelGGL(pv_out, dim3(16, BATCH * NH), dim3(512), 0, stream,
                     Wsmb, PvT, Pv2T, Svw, Wv2b, VTb, bv2, outp);
}

// Round 12
// 56.956 us; speedup vs baseline: 1.4406x; 1.1772x over previous
//
#include <hip/hip_runtime.h>

#define BATCH 2
#define NTOK 256
#define DM 512
#define NH 8
#define HDIM 64
#define PD 520      // bf16 row stride for d-major (k=512) pair tensors
#define TSTR 264    // bf16 row stride for j-major (k=256) tensors
#define WSTR 264

typedef unsigned int uint32;
typedef unsigned short ushort16;
typedef __attribute__((ext_vector_type(8))) short bf16x8;
typedef __attribute__((ext_vector_type(4))) float f32x4;

static __device__ __forceinline__ ushort16 bf16_rne(float x) {
  uint32 u = __float_as_uint(x);
  u += 0x7fffu + ((u >> 16) & 1u);
  return (ushort16)(u >> 16);
}
static __device__ __forceinline__ uint32 pack2(float a, float b) {
  return (uint32)bf16_rne(a) | ((uint32)bf16_rne(b) << 16);
}

// 16x32 bf16 MFMA fragment from row-major [16dim][k]: lane l -> row l&15, k-off (l>>4)*8
static __device__ __forceinline__ bf16x8 ldfrag(const ushort16* p0, int stride) {
  int l = threadIdx.x & 63;
  return *(const bf16x8*)(p0 + (size_t)(l & 15) * stride + ((l >> 4) << 3));
}

// ---------------- stage0: prep tables (blocks 0-127) + bf16 conversion (128-767) ----
// conv: x (128 blocks), Wqkv (384), Wv2 (128); 2048 floats/block, uint4 packed stores.
__global__ __launch_bounds__(256) void stage0(
    const float* __restrict__ coords,
    const float* __restrict__ Wb1, const float* __restrict__ bb1,
    const float* __restrict__ Wv1, const float* __restrict__ bv1,
    const float* __restrict__ Wb2,
    const float* __restrict__ X, const float* __restrict__ Wqkv,
    const float* __restrict__ Wv2,
    float* __restrict__ Sv, ushort16* __restrict__ SbW,
    ushort16* __restrict__ Pb, ushort16* __restrict__ PvT,
    ushort16* __restrict__ Pv2T, float* __restrict__ DjT,
    ushort16* __restrict__ xb, ushort16* __restrict__ Wqb,
    ushort16* __restrict__ Wv2b) {
  int t = threadIdx.x;
  int bx = blockIdx.x;
  if (bx >= 128) {
    // ---- flat fp32 -> bf16 conversion ----
    const float* src; ushort16* dst; int cb;
    if (bx < 256)      { src = X;    dst = xb;   cb = bx - 128; }
    else if (bx < 640) { src = Wqkv; dst = Wqb;  cb = bx - 256; }
    else               { src = Wv2;  dst = Wv2b; cb = bx - 640; }
    size_t off = ((size_t)cb * 256 + t) * 8;
    float4 f1 = *(const float4*)(src + off);
    float4 f2 = *(const float4*)(src + off + 4);
    uint4 pk;
    pk.x = pack2(f1.x, f1.y); pk.y = pack2(f1.z, f1.w);
    pk.z = pack2(f2.x, f2.y); pk.w = pack2(f2.z, f2.w);
    *(uint4*)&dst[off] = pk;
    return;
  }
  // ---- prep path: 4 tokens per block, d = {2t, 2t+1} per thread ----
  __shared__ float redD[4][8];
  int b = bx >> 6;
  int t0 = (bx & 63) * 4;
  int lane = t & 63, wv = t >> 6;
  int d0 = t * 2, d1 = t * 2 + 1;
  float w2a[NH], w2b[NH];
#pragma unroll
  for (int h = 0; h < NH; ++h) {
    w2a[h] = Wb2[h * DM + d0];
    w2b[h] = Wb2[h * DM + d1];
  }
  float b1ax = Wb1[d0 * 3 + 0], b1ay = Wb1[d0 * 3 + 1], b1az = Wb1[d0 * 3 + 2];
  float b1bx = Wb1[d1 * 3 + 0], b1by = Wb1[d1 * 3 + 1], b1bz = Wb1[d1 * 3 + 2];
  float v1ax = Wv1[d0 * 3 + 0], v1ay = Wv1[d0 * 3 + 1], v1az = Wv1[d0 * 3 + 2];
  float v1bx = Wv1[d1 * 3 + 0], v1by = Wv1[d1 * 3 + 1], v1bz = Wv1[d1 * 3 + 2];
  float bba = bb1[d0], bbb = bb1[d1];
  float bva = bv1[d0], bvb = bv1[d1];
  ushort16 pvp[2][4], pv2p[2][4];
#pragma unroll
  for (int tt = 0; tt < 4; ++tt) {
    int tok = t0 + tt, q = b * NTOK + tok;
    const float* cp = coords + q * 3;          // uniform -> s_load
    float c0 = cp[0], c1 = cp[1], c2 = cp[2];
    float pba = b1ax * c0 + b1ay * c1 + b1az * c2;
    float pbb = b1bx * c0 + b1by * c1 + b1bz * c2;
    float pva = v1ax * c0 + v1ay * c1 + v1az * c2;
    float pvb = v1bx * c0 + v1by * c1 + v1bz * c2;
    float sba = pba + bba, sbb = pbb + bbb;
    *(float2*)&Sv[(size_t)q * DM + d0] = make_float2(pva + bva, pvb + bvb);
    *(uint32*)&Pb[(size_t)q * PD + d0] = pack2(pba, pbb);
    pvp[0][tt] = bf16_rne(pva);
    pvp[1][tt] = bf16_rne(pvb);
    pv2p[0][tt] = bf16_rne(pva * pva);
    pv2p[1][tt] = bf16_rne(pvb * pvb);
#pragma unroll
    for (int h = 0; h < NH; ++h) {
      size_t base = ((size_t)(b * NH + h) * NTOK + tok) * PD;
      *(uint32*)&SbW[base + d0] = pack2(-0.5f * w2a[h] * sba, -0.5f * w2b[h] * sbb);
    }
    float ua = -0.5f * pba + 0.25f * pba * pba;
    float ub = -0.5f * pbb + 0.25f * pbb * pbb;
    float dp[NH];
#pragma unroll
    for (int h = 0; h < NH; ++h) dp[h] = fmaf(w2a[h], ua, w2b[h] * ub);
#pragma unroll
    for (int off = 32; off >= 1; off >>= 1) {
#pragma unroll
      for (int h = 0; h < NH; ++h) dp[h] += __shfl_xor(dp[h], off);
    }
    if (lane == 0) {
#pragma unroll
      for (int h = 0; h < NH; ++h) redD[wv][h] = dp[h];
    }
    __syncthreads();
    if (t < NH)
      DjT[(size_t)(b * NH + t) * NTOK + tok] =
          (redD[0][t] + redD[1][t]) + (redD[2][t] + redD[3][t]);
    __syncthreads();
  }
  uint2 k1, k2;
#pragma unroll
  for (int hh = 0; hh < 2; ++hh) {
    int d = t * 2 + hh;
    k1.x = (uint32)pvp[hh][0] | ((uint32)pvp[hh][1] << 16);
    k1.y = (uint32)pvp[hh][2] | ((uint32)pvp[hh][3] << 16);
    k2.x = (uint32)pv2p[hh][0] | ((uint32)pv2p[hh][1] << 16);
    k2.y = (uint32)pv2p[hh][2] | ((uint32)pv2p[hh][3] << 16);
    *(uint2*)&PvT [((size_t)(b * DM) + d) * TSTR + t0] = k1;
    *(uint2*)&Pv2T[((size_t)(b * DM) + d) * TSTR + t0] = k2;
  }
}

// ---------------- qkv_mfma: qkv = x @ Wqkv^T + bqkv (bf16 MFMA, no LDS) ----------
// grid (12 n-tiles of 128, 32 i-tiles), 128 thr = 2 waves; wave = 16i x 64n, K=512.
__global__ __launch_bounds__(128) void qkv_mfma(
    const ushort16* __restrict__ xb, const ushort16* __restrict__ Wqb,
    const float* __restrict__ bqkv,
    ushort16* __restrict__ Qb, ushort16* __restrict__ Kb,
    ushort16* __restrict__ VTb) {
  int t = threadIdx.x;
  int w = t >> 6, lane = t & 63;
  int n0 = blockIdx.x * 128 + w * 64;   // 64-aligned -> single section+head per wave
  int ibase = blockIdx.y * 16;
  f32x4 acc[4] = {};
  const ushort16* abase = xb + (size_t)ibase * DM;
  const ushort16* bbase = Wqb + (size_t)n0 * DM;
#pragma unroll 4
  for (int kb = 0; kb < 16; ++kb) {
    bf16x8 af = ldfrag(abase + kb * 32, DM);
#pragma unroll
    for (int nf = 0; nf < 4; ++nf) {
      bf16x8 bf = ldfrag(bbase + (size_t)nf * 16 * DM + kb * 32, DM);
      acc[nf] = __builtin_amdgcn_mfma_f32_16x16x32_bf16(af, bf, acc[nf], 0, 0, 0);
    }
  }
  int col = lane & 15, rb = (lane >> 4) * 4;
#pragma unroll
  for (int nf = 0; nf < 4; ++nf) {
#pragma unroll
    for (int r = 0; r < 4; ++r) {
      int n = n0 + nf * 16 + col;
      int ig = ibase + rb + r;
      int b = ig >> 8, i = ig & (NTOK - 1);
      float val = acc[nf][r] + bqkv[n];
      if (n < DM) {
        int h = n >> 6, dp = (nf * 16 + col) & 63;
        Qb[((size_t)(b * NH + h) * NTOK + i) * HDIM + dp] = bf16_rne(val * 0.125f);
      } else if (n < 2 * DM) {
        int u = n - DM; int h = u >> 6, dp = u & 63;
        Kb[((size_t)(b * NH + h) * NTOK + i) * HDIM + dp] = bf16_rne(val);
      } else {
        int u = n - 2 * DM; int h = u >> 6, dp = u & 63;
        VTb[((size_t)(b * NH + h) * HDIM + dp) * TSTR + i] = bf16_rne(val);
      }
    }
  }
}

// ---------------- score_softmax (MFMA + fused softmax), 8 waves ----------------
// grid (16 i-tiles, 16 bh), 512 thr. Wave w: 16i x 32j strip (j0 = w*32).
__global__ __launch_bounds__(512) void score_softmax(
    const ushort16* __restrict__ Qb, const ushort16* __restrict__ Kb,
    const ushort16* __restrict__ SbW, const ushort16* __restrict__ Pb,
    const float* __restrict__ DjT, ushort16* __restrict__ Wsmb) {
  __shared__ float redm[8][16];
  __shared__ float reds[8][16];
  int t = threadIdx.x;
  int w = t >> 6, lane = t & 63;
  int bh = blockIdx.y;
  int b = bh >> 3;
  int ib = blockIdx.x * 16;
  int j0 = w * 32;
  int col = lane & 15, rb = (lane >> 4) * 4;
  f32x4 acc[2] = {};
  {  // qk over K=64
    const ushort16* qbase = Qb + ((size_t)bh * NTOK + ib) * HDIM;
    const ushort16* kbase = Kb + ((size_t)bh * NTOK + j0) * HDIM;
#pragma unroll
    for (int kb = 0; kb < 2; ++kb) {
      bf16x8 af = ldfrag(qbase + kb * 32, HDIM);
#pragma unroll
      for (int jf = 0; jf < 2; ++jf) {
        bf16x8 bf = ldfrag(kbase + (size_t)jf * 16 * HDIM + kb * 32, HDIM);
        acc[jf] = __builtin_amdgcn_mfma_f32_16x16x32_bf16(af, bf, acc[jf], 0, 0, 0);
      }
    }
  }
  {  // C-term over K=512 (-0.5 folded into SbW)
    const ushort16* abase = SbW + ((size_t)bh * NTOK + ib) * PD;
    const ushort16* bbase = Pb + ((size_t)(b * NTOK) + j0) * PD;
#pragma unroll 4
    for (int kb = 0; kb < 16; ++kb) {
      bf16x8 af = ldfrag(abase + kb * 32, PD);
#pragma unroll
      for (int jf = 0; jf < 2; ++jf) {
        bf16x8 bf = ldfrag(bbase + (size_t)jf * 16 * PD + kb * 32, PD);
        acc[jf] = __builtin_amdgcn_mfma_f32_16x16x32_bf16(af, bf, acc[jf], 0, 0, 0);
      }
    }
  }
  float sc[2][4];
#pragma unroll
  for (int jf = 0; jf < 2; ++jf) {
    float dj = DjT[(size_t)bh * NTOK + j0 + jf * 16 + col];
#pragma unroll
    for (int r = 0; r < 4; ++r) sc[jf][r] = acc[jf][r] + dj;
  }
#pragma unroll
  for (int r = 0; r < 4; ++r) {
    float m = fmaxf(sc[0][r], sc[1][r]);
    m = fmaxf(m, __shfl_xor(m, 1));
    m = fmaxf(m, __shfl_xor(m, 2));
    m = fmaxf(m, __shfl_xor(m, 4));
    m = fmaxf(m, __shfl_xor(m, 8));
    if (col == 0) redm[w][rb + r] = m;
  }
  __syncthreads();
  float mrow[4];
#pragma unroll
  for (int r = 0; r < 4; ++r) {
    float m = redm[0][rb + r];
#pragma unroll
    for (int ww = 1; ww < 8; ++ww) m = fmaxf(m, redm[ww][rb + r]);
    mrow[r] = m;
  }
#pragma unroll
  for (int r = 0; r < 4; ++r) {
    float su = 0.f;
#pragma unroll
    for (int jf = 0; jf < 2; ++jf) {
      float e = __expf(sc[jf][r] - mrow[r]);
      sc[jf][r] = e;
      su += e;
    }
    su += __shfl_xor(su, 1);
    su += __shfl_xor(su, 2);
    su += __shfl_xor(su, 4);
    su += __shfl_xor(su, 8);
    if (col == 0) reds[w][rb + r] = su;
  }
  __syncthreads();
#pragma unroll
  for (int r = 0; r < 4; ++r) {
    float stot = 0.f;
#pragma unroll
    for (int ww = 0; ww < 8; ++ww) stot += reds[ww][rb + r];
    float inv = __builtin_amdgcn_rcpf(stot);
    int row = ib + rb + r;
#pragma unroll
    for (int jf = 0; jf < 2; ++jf)
      Wsmb[((size_t)bh * NTOK + row) * WSTR + j0 + jf * 16 + col] = bf16_rne(sc[jf][r] * inv);
  }
}

// ---------------- pv_out (MFMA), 8 waves ----------------
// Phase A: wave w -> P1/P2 for 16i x 64d (d0=w*64), K=256; Taylor g -> LDS bf16.
// Phase B: waves 0-3 -> g@Wv2^T (K=512) o-strip w*16 into LDS float;
//          waves 4-7 -> Wsm@V (K=256) o-strip (w-4)*16; combine + bv2 -> out.
__global__ __launch_bounds__(512) void pv_out(
    const ushort16* __restrict__ Wsmb, const ushort16* __restrict__ PvT,
    const ushort16* __restrict__ Pv2T, const float* __restrict__ Sv,
    const ushort16* __restrict__ Wv2b, const ushort16* __restrict__ VTb,
    const float* __restrict__ bv2, float* __restrict__ out) {
  __shared__ ushort16 gsh[16][DM + 8];   // 16.6 KB
  __shared__ float fB[16][68];           // 4.3 KB
  int t = threadIdx.x;
  int w = t >> 6, lane = t & 63;
  int bh = blockIdx.y;
  int b = bh >> 3, h = bh & 7;
  int ib = blockIdx.x * 16;
  int col = lane & 15, rb = (lane >> 4) * 4;
  const ushort16* abase = Wsmb + ((size_t)bh * NTOK + ib) * WSTR;

  // ---- phase A ----
  int d0 = w * 64;
  f32x4 a1[4] = {}, a2[4] = {};
  {
    const ushort16* b1 = PvT + ((size_t)(b * DM) + d0) * TSTR;
    const ushort16* b2 = Pv2T + ((size_t)(b * DM) + d0) * TSTR;
#pragma unroll 2
    for (int kb = 0; kb < 8; ++kb) {
      bf16x8 af = ldfrag(abase + kb * 32, WSTR);
#pragma unroll
      for (int df = 0; df < 4; ++df) {
        bf16x8 f1 = ldfrag(b1 + (size_t)df * 16 * TSTR + kb * 32, TSTR);
        a1[df] = __builtin_amdgcn_mfma_f32_16x16x32_bf16(af, f1, a1[df], 0, 0, 0);
        bf16x8 f2 = ldfrag(b2 + (size_t)df * 16 * TSTR + kb * 32, TSTR);
        a2[df] = __builtin_amdgcn_mfma_f32_16x16x32_bf16(af, f2, a2[df], 0, 0, 0);
      }
    }
  }
#pragma unroll
  for (int df = 0; df < 4; ++df) {
#pragma unroll
    for (int r = 0; r < 4; ++r) {
      int ig = ib + rb + r;
      int dg = d0 + df * 16 + col;
      float sv = Sv[((size_t)(b * NTOK) + ig) * DM + dg];
      float p1 = a1[df][r], p2 = a2[df][r];
      float g = 0.5f * (sv - p1) + 0.25f * (sv * sv - 2.f * sv * p1 + p2);
      gsh[rb + r][dg] = bf16_rne(g);
    }
  }
  __syncthreads();

  // ---- phase B (split K-work across wave halves) ----
  f32x4 acc2 = {};
  if (w < 4) {  // g @ Wv2_h^T, K=512, A from LDS
    const ushort16* wvb = Wv2b + (size_t)(h * HDIM + w * 16) * DM;
#pragma unroll 4
    for (int kb = 0; kb < 16; ++kb) {
      bf16x8 af = *(const bf16x8*)&gsh[col][kb * 32 + ((lane >> 4) << 3)];
      bf16x8 bf = ldfrag(wvb + kb * 32, DM);
      acc2 = __builtin_amdgcn_mfma_f32_16x16x32_bf16(af, bf, acc2, 0, 0, 0);
    }
  } else {      // Wsm @ V, K=256
    const ushort16* vtb = VTb + (size_t)(bh * HDIM + (w - 4) * 16) * TSTR;
#pragma unroll 2
    for (int kb = 0; kb < 8; ++kb) {
      bf16x8 af = ldfrag(abase + kb * 32, WSTR);
      bf16x8 bf = ldfrag(vtb + kb * 32, TSTR);
      acc2 = __builtin_amdgcn_mfma_f32_16x16x32_bf16(af, bf, acc2, 0, 0, 0);
    }
  }
  if (w < 4) {
#pragma unroll
    for (int r = 0; r < 4; ++r) fB[rb + r][w * 16 + col] = acc2[r];
  }
  __syncthreads();
  if (w >= 4) {
    int o = h * HDIM + (w - 4) * 16 + col;
    float bv = bv2[o];
#pragma unroll
    for (int r = 0; r < 4; ++r) {
      int ig = ib + rb + r;
      out[((size_t)(b * NTOK) + ig) * DM + o] = fB[rb + r][(w - 4) * 16 + col] + acc2[r] + bv;
    }
  }
}

extern "C" void kernel_launch(void* const* d_in, const int* in_sizes, int n_in,
                              void* d_out, int out_size, void* d_ws, size_t ws_size,
                              hipStream_t stream) {
  const float* x      = (const float*)d_in[0];
  const float* coords = (const float*)d_in[1];
  const float* Wqkv   = (const float*)d_in[2];
  const float* bqkv   = (const float*)d_in[3];
  const float* Wb1    = (const float*)d_in[4];
  const float* bb1    = (const float*)d_in[5];
  const float* Wb2    = (const float*)d_in[6];
  // d_in[7] = bb2: softmax-invariant, unused
  const float* Wv1    = (const float*)d_in[8];
  const float* bv1    = (const float*)d_in[9];
  const float* Wv2    = (const float*)d_in[10];
  const float* bv2    = (const float*)d_in[11];
  float* outp = (float*)d_out;
  float* ws = (float*)d_ws;

  const size_t SZ = (size_t)BATCH * NTOK * DM;           // 262144
  float* Svw = ws;
  float* DjT = ws + SZ;                                  // [bh][j], 4096 floats
  ushort16* SbW  = (ushort16*)(DjT + 4096);              // [bh][tok][PD]
  ushort16* Pbw  = SbW + (size_t)BATCH * NH * NTOK * PD;
  ushort16* PvT  = Pbw + (size_t)BATCH * NTOK * PD;      // [b][d][TSTR]
  ushort16* Pv2T = PvT + (size_t)BATCH * DM * TSTR;
  ushort16* Wsmb = Pv2T + (size_t)BATCH * DM * TSTR;     // [bh][i][WSTR]
  ushort16* Qb   = Wsmb + (size_t)BATCH * NH * NTOK * WSTR;  // [bh][i][64]
  ushort16* Kb   = Qb + (size_t)BATCH * NH * NTOK * HDIM;
  ushort16* VTb  = Kb + (size_t)BATCH * NH * NTOK * HDIM;    // [bh][dp][TSTR]
  ushort16* xb   = VTb + (size_t)BATCH * NH * HDIM * TSTR;   // [row][DM]
  ushort16* Wqb  = xb + (size_t)BATCH * NTOK * DM;           // [n][DM]
  ushort16* Wv2b = Wqb + (size_t)3 * DM * DM;                // [o][DM]

  hipLaunchKernelGGL(stage0, dim3(768), dim3(256), 0, stream,
                     coords, Wb1, bb1, Wv1, bv1, Wb2, x, Wqkv, Wv2,
                     Svw, SbW, Pbw, PvT, Pv2T, DjT, xb, Wqb, Wv2b);
  hipLaunchKernelGGL(qkv_mfma, dim3(12, 32), dim3(128), 0, stream,
                     xb, Wqb, bqkv, Qb, Kb, VTb);
  hipLaunchKernelGGL(score_softmax, dim3(16, BATCH * NH), dim3(512), 0, stream,
                     Qb, Kb, SbW, Pbw, DjT, Wsmb);
  hipLaunchKernelGGL(pv_out, dim3(16, BATCH * NH), dim3(512), 0, stream,
                     Wsmb, PvT, Pv2T, Svw, Wv2b, VTb, bv2, outp);
}

// Round 13
// 54.865 us; speedup vs baseline: 1.4955x; 1.0381x over previous
//
#include <hip/hip_runtime.h>

#define BATCH 2
#define NTOK 256
#define DM 512
#define NH 8
#define HDIM 64
#define PD 520      // bf16 row stride for d-major (k=512) pair tensors
#define TSTR 264    // bf16 row stride for j-major (k=256) tensors
#define WSTR 264

typedef unsigned int uint32;
typedef unsigned short ushort16;
typedef __attribute__((ext_vector_type(8))) short bf16x8;
typedef __attribute__((ext_vector_type(4))) float f32x4;

static __device__ __forceinline__ ushort16 bf16_rne(float x) {
  uint32 u = __float_as_uint(x);
  u += 0x7fffu + ((u >> 16) & 1u);
  return (ushort16)(u >> 16);
}
static __device__ __forceinline__ uint32 pack2(float a, float b) {
  return (uint32)bf16_rne(a) | ((uint32)bf16_rne(b) << 16);
}

// 16x32 bf16 MFMA fragment from row-major [16dim][k]: lane l -> row l&15, k-off (l>>4)*8
static __device__ __forceinline__ bf16x8 ldfrag(const ushort16* p0, int stride) {
  int l = threadIdx.x & 63;
  return *(const bf16x8*)(p0 + (size_t)(l & 15) * stride + ((l >> 4) << 3));
}

// ---------------- stage0: prep tables (blocks 0-127) + bf16 conversion (128-767) ----
__global__ __launch_bounds__(256) void stage0(
    const float* __restrict__ coords,
    const float* __restrict__ Wb1, const float* __restrict__ bb1,
    const float* __restrict__ Wv1, const float* __restrict__ bv1,
    const float* __restrict__ Wb2,
    const float* __restrict__ X, const float* __restrict__ Wqkv,
    const float* __restrict__ Wv2,
    float* __restrict__ Sv, ushort16* __restrict__ SbW,
    ushort16* __restrict__ Pb, ushort16* __restrict__ PvT,
    ushort16* __restrict__ Pv2T, float* __restrict__ DjT,
    ushort16* __restrict__ xb, ushort16* __restrict__ Wqb,
    ushort16* __restrict__ Wv2b) {
  int t = threadIdx.x;
  int bx = blockIdx.x;
  if (bx >= 128) {
    // ---- flat fp32 -> bf16 conversion ----
    const float* src; ushort16* dst; int cb;
    if (bx < 256)      { src = X;    dst = xb;   cb = bx - 128; }
    else if (bx < 640) { src = Wqkv; dst = Wqb;  cb = bx - 256; }
    else               { src = Wv2;  dst = Wv2b; cb = bx - 640; }
    size_t off = ((size_t)cb * 256 + t) * 8;
    float4 f1 = *(const float4*)(src + off);
    float4 f2 = *(const float4*)(src + off + 4);
    uint4 pk;
    pk.x = pack2(f1.x, f1.y); pk.y = pack2(f1.z, f1.w);
    pk.z = pack2(f2.x, f2.y); pk.w = pack2(f2.z, f2.w);
    *(uint4*)&dst[off] = pk;
    return;
  }
  // ---- prep path: 4 tokens per block, d = {2t, 2t+1} per thread ----
  __shared__ float redD[4][8];
  int b = bx >> 6;
  int t0 = (bx & 63) * 4;
  int lane = t & 63, wv = t >> 6;
  int d0 = t * 2, d1 = t * 2 + 1;
  float w2a[NH], w2b[NH];
#pragma unroll
  for (int h = 0; h < NH; ++h) {
    w2a[h] = Wb2[h * DM + d0];
    w2b[h] = Wb2[h * DM + d1];
  }
  float b1ax = Wb1[d0 * 3 + 0], b1ay = Wb1[d0 * 3 + 1], b1az = Wb1[d0 * 3 + 2];
  float b1bx = Wb1[d1 * 3 + 0], b1by = Wb1[d1 * 3 + 1], b1bz = Wb1[d1 * 3 + 2];
  float v1ax = Wv1[d0 * 3 + 0], v1ay = Wv1[d0 * 3 + 1], v1az = Wv1[d0 * 3 + 2];
  float v1bx = Wv1[d1 * 3 + 0], v1by = Wv1[d1 * 3 + 1], v1bz = Wv1[d1 * 3 + 2];
  float bba = bb1[d0], bbb = bb1[d1];
  float bva = bv1[d0], bvb = bv1[d1];
  ushort16 pvp[2][4], pv2p[2][4];
#pragma unroll
  for (int tt = 0; tt < 4; ++tt) {
    int tok = t0 + tt, q = b * NTOK + tok;
    const float* cp = coords + q * 3;          // uniform -> s_load
    float c0 = cp[0], c1 = cp[1], c2 = cp[2];
    float pba = b1ax * c0 + b1ay * c1 + b1az * c2;
    float pbb = b1bx * c0 + b1by * c1 + b1bz * c2;
    float pva = v1ax * c0 + v1ay * c1 + v1az * c2;
    float pvb = v1bx * c0 + v1by * c1 + v1bz * c2;
    float sba = pba + bba, sbb = pbb + bbb;
    *(float2*)&Sv[(size_t)q * DM + d0] = make_float2(pva + bva, pvb + bvb);
    *(uint32*)&Pb[(size_t)q * PD + d0] = pack2(pba, pbb);
    pvp[0][tt] = bf16_rne(pva);
    pvp[1][tt] = bf16_rne(pvb);
    pv2p[0][tt] = bf16_rne(pva * pva);
    pv2p[1][tt] = bf16_rne(pvb * pvb);
#pragma unroll
    for (int h = 0; h < NH; ++h) {
      size_t base = ((size_t)(b * NH + h) * NTOK + tok) * PD;
      *(uint32*)&SbW[base + d0] = pack2(-0.5f * w2a[h] * sba, -0.5f * w2b[h] * sbb);
    }
    float ua = -0.5f * pba + 0.25f * pba * pba;
    float ub = -0.5f * pbb + 0.25f * pbb * pbb;
    float dp[NH];
#pragma unroll
    for (int h = 0; h < NH; ++h) dp[h] = fmaf(w2a[h], ua, w2b[h] * ub);
#pragma unroll
    for (int off = 32; off >= 1; off >>= 1) {
#pragma unroll
      for (int h = 0; h < NH; ++h) dp[h] += __shfl_xor(dp[h], off);
    }
    if (lane == 0) {
#pragma unroll
      for (int h = 0; h < NH; ++h) redD[wv][h] = dp[h];
    }
    __syncthreads();
    if (t < NH)
      DjT[(size_t)(b * NH + t) * NTOK + tok] =
          (redD[0][t] + redD[1][t]) + (redD[2][t] + redD[3][t]);
    __syncthreads();
  }
  uint2 k1, k2;
#pragma unroll
  for (int hh = 0; hh < 2; ++hh) {
    int d = t * 2 + hh;
    k1.x = (uint32)pvp[hh][0] | ((uint32)pvp[hh][1] << 16);
    k1.y = (uint32)pvp[hh][2] | ((uint32)pvp[hh][3] << 16);
    k2.x = (uint32)pv2p[hh][0] | ((uint32)pv2p[hh][1] << 16);
    k2.y = (uint32)pv2p[hh][2] | ((uint32)pv2p[hh][3] << 16);
    *(uint2*)&PvT [((size_t)(b * DM) + d) * TSTR + t0] = k1;
    *(uint2*)&Pv2T[((size_t)(b * DM) + d) * TSTR + t0] = k2;
  }
}

// ---------------- qkv_mfma: qkv = x @ Wqkv^T + bqkv (bf16 MFMA, no LDS) ----------
// grid (12 n-tiles of 128, 32 i-tiles), 128 thr = 2 waves; wave = 16i x 64n, K=512.
__global__ __launch_bounds__(128) void qkv_mfma(
    const ushort16* __restrict__ xb, const ushort16* __restrict__ Wqb,
    const float* __restrict__ bqkv,
    ushort16* __restrict__ Qb, ushort16* __restrict__ Kb,
    ushort16* __restrict__ VTb) {
  int t = threadIdx.x;
  int w = t >> 6, lane = t & 63;
  int n0 = blockIdx.x * 128 + w * 64;   // 64-aligned -> single section+head per wave
  int ibase = blockIdx.y * 16;
  f32x4 acc[4] = {};
  const ushort16* abase = xb + (size_t)ibase * DM;
  const ushort16* bbase = Wqb + (size_t)n0 * DM;
#pragma unroll 4
  for (int kb = 0; kb < 16; ++kb) {
    bf16x8 af = ldfrag(abase + kb * 32, DM);
#pragma unroll
    for (int nf = 0; nf < 4; ++nf) {
      bf16x8 bf = ldfrag(bbase + (size_t)nf * 16 * DM + kb * 32, DM);
      acc[nf] = __builtin_amdgcn_mfma_f32_16x16x32_bf16(af, bf, acc[nf], 0, 0, 0);
    }
  }
  int col = lane & 15, rb = (lane >> 4) * 4;
#pragma unroll
  for (int nf = 0; nf < 4; ++nf) {
#pragma unroll
    for (int r = 0; r < 4; ++r) {
      int n = n0 + nf * 16 + col;
      int ig = ibase + rb + r;
      int b = ig >> 8, i = ig & (NTOK - 1);
      float val = acc[nf][r] + bqkv[n];
      if (n < DM) {
        int h = n >> 6, dp = (nf * 16 + col) & 63;
        Qb[((size_t)(b * NH + h) * NTOK + i) * HDIM + dp] = bf16_rne(val * 0.125f);
      } else if (n < 2 * DM) {
        int u = n - DM; int h = u >> 6, dp = u & 63;
        Kb[((size_t)(b * NH + h) * NTOK + i) * HDIM + dp] = bf16_rne(val);
      } else {
        int u = n - 2 * DM; int h = u >> 6, dp = u & 63;
        VTb[((size_t)(b * NH + h) * HDIM + dp) * TSTR + i] = bf16_rne(val);
      }
    }
  }
}

// ---------------- attn_fused2: scores + softmax (LDS) + P1/P2 + Taylor g + out ------
// grid (16 i-tiles, 16 bh), 512 thr = 8 waves; same 8-wave structure as the R12 split:
// score: wave w = 16i x 32j strip; phase A: wave w = 64-d strip;
// phase B: waves 0-3 g@Wv2^T, waves 4-7 Wsm@V, combine via LDS.
__global__ __launch_bounds__(512) void attn_fused2(
    const ushort16* __restrict__ Qb, const ushort16* __restrict__ Kb,
    const ushort16* __restrict__ SbW, const ushort16* __restrict__ Pb,
    const float* __restrict__ DjT,
    const ushort16* __restrict__ PvT, const ushort16* __restrict__ Pv2T,
    const float* __restrict__ Sv,
    const ushort16* __restrict__ Wv2b, const ushort16* __restrict__ VTb,
    const float* __restrict__ bv2, float* __restrict__ out) {
  __shared__ ushort16 wsh[16][WSTR];     // softmax weights bf16 (8.4 KB)
  __shared__ ushort16 gsh[16][DM + 8];   // g bf16 (16.6 KB)
  __shared__ float fB[16][68];           // 4.3 KB
  __shared__ float redm[8][16];
  __shared__ float reds[8][16];
  int t = threadIdx.x;
  int w = t >> 6, lane = t & 63;
  int bh = blockIdx.y;
  int b = bh >> 3, h = bh & 7;
  int ib = blockIdx.x * 16;
  int col = lane & 15, rb = (lane >> 4) * 4;

  // ======== score: wave w covers j0 = w*32 ========
  {
    int j0 = w * 32;
    f32x4 acc[2] = {};
    {  // qk over K=64
      const ushort16* qbase = Qb + ((size_t)bh * NTOK + ib) * HDIM;
      const ushort16* kbase = Kb + ((size_t)bh * NTOK + j0) * HDIM;
#pragma unroll
      for (int kb = 0; kb < 2; ++kb) {
        bf16x8 af = ldfrag(qbase + kb * 32, HDIM);
#pragma unroll
        for (int jf = 0; jf < 2; ++jf) {
          bf16x8 bf = ldfrag(kbase + (size_t)jf * 16 * HDIM + kb * 32, HDIM);
          acc[jf] = __builtin_amdgcn_mfma_f32_16x16x32_bf16(af, bf, acc[jf], 0, 0, 0);
        }
      }
    }
    {  // C-term over K=512 (-0.5 folded into SbW)
      const ushort16* abase = SbW + ((size_t)bh * NTOK + ib) * PD;
      const ushort16* bbase = Pb + ((size_t)(b * NTOK) + j0) * PD;
#pragma unroll 4
      for (int kb = 0; kb < 16; ++kb) {
        bf16x8 af = ldfrag(abase + kb * 32, PD);
#pragma unroll
        for (int jf = 0; jf < 2; ++jf) {
          bf16x8 bf = ldfrag(bbase + (size_t)jf * 16 * PD + kb * 32, PD);
          acc[jf] = __builtin_amdgcn_mfma_f32_16x16x32_bf16(af, bf, acc[jf], 0, 0, 0);
        }
      }
    }
    float sc[2][4];
#pragma unroll
    for (int jf = 0; jf < 2; ++jf) {
      float dj = DjT[(size_t)bh * NTOK + j0 + jf * 16 + col];
#pragma unroll
      for (int r = 0; r < 4; ++r) sc[jf][r] = acc[jf][r] + dj;
    }
#pragma unroll
    for (int r = 0; r < 4; ++r) {
      float m = fmaxf(sc[0][r], sc[1][r]);
      m = fmaxf(m, __shfl_xor(m, 1));
      m = fmaxf(m, __shfl_xor(m, 2));
      m = fmaxf(m, __shfl_xor(m, 4));
      m = fmaxf(m, __shfl_xor(m, 8));
      if (col == 0) redm[w][rb + r] = m;
    }
    __syncthreads();
    float mrow[4];
#pragma unroll
    for (int r = 0; r < 4; ++r) {
      float m = redm[0][rb + r];
#pragma unroll
      for (int ww = 1; ww < 8; ++ww) m = fmaxf(m, redm[ww][rb + r]);
      mrow[r] = m;
    }
#pragma unroll
    for (int r = 0; r < 4; ++r) {
      float su = 0.f;
#pragma unroll
      for (int jf = 0; jf < 2; ++jf) {
        float e = __expf(sc[jf][r] - mrow[r]);
        sc[jf][r] = e;
        su += e;
      }
      su += __shfl_xor(su, 1);
      su += __shfl_xor(su, 2);
      su += __shfl_xor(su, 4);
      su += __shfl_xor(su, 8);
      if (col == 0) reds[w][rb + r] = su;
    }
    __syncthreads();
#pragma unroll
    for (int r = 0; r < 4; ++r) {
      float stot = 0.f;
#pragma unroll
      for (int ww = 0; ww < 8; ++ww) stot += reds[ww][rb + r];
      float inv = __builtin_amdgcn_rcpf(stot);
#pragma unroll
      for (int jf = 0; jf < 2; ++jf)
        wsh[rb + r][j0 + jf * 16 + col] = bf16_rne(sc[jf][r] * inv);
    }
  }
  __syncthreads();

  // ======== phase A: P1/P2 for d0 = w*64, K=256, A (Wsm) from LDS ========
  {
    int d0 = w * 64;
    f32x4 a1[4] = {}, a2[4] = {};
    const ushort16* b1 = PvT + ((size_t)(b * DM) + d0) * TSTR;
    const ushort16* b2 = Pv2T + ((size_t)(b * DM) + d0) * TSTR;
#pragma unroll 2
    for (int kb = 0; kb < 8; ++kb) {
      bf16x8 af = *(const bf16x8*)&wsh[col][kb * 32 + ((lane >> 4) << 3)];
#pragma unroll
      for (int df = 0; df < 4; ++df) {
        bf16x8 f1 = ldfrag(b1 + (size_t)df * 16 * TSTR + kb * 32, TSTR);
        a1[df] = __builtin_amdgcn_mfma_f32_16x16x32_bf16(af, f1, a1[df], 0, 0, 0);
        bf16x8 f2 = ldfrag(b2 + (size_t)df * 16 * TSTR + kb * 32, TSTR);
        a2[df] = __builtin_amdgcn_mfma_f32_16x16x32_bf16(af, f2, a2[df], 0, 0, 0);
      }
    }
#pragma unroll
    for (int df = 0; df < 4; ++df) {
#pragma unroll
      for (int r = 0; r < 4; ++r) {
        int ig = ib + rb + r;
        int dg = d0 + df * 16 + col;
        float sv = Sv[((size_t)(b * NTOK) + ig) * DM + dg];
        float p1 = a1[df][r], p2 = a2[df][r];
        float g = 0.5f * (sv - p1) + 0.25f * (sv * sv - 2.f * sv * p1 + p2);
        gsh[rb + r][dg] = bf16_rne(g);
      }
    }
  }
  __syncthreads();

  // ======== phase B: split K-work across wave halves ========
  f32x4 acc2 = {};
  if (w < 4) {  // g @ Wv2_h^T, K=512, A from LDS
    const ushort16* wvb = Wv2b + (size_t)(h * HDIM + w * 16) * DM;
#pragma unroll 4
    for (int kb = 0; kb < 16; ++kb) {
      bf16x8 af = *(const bf16x8*)&gsh[col][kb * 32 + ((lane >> 4) << 3)];
      bf16x8 bf = ldfrag(wvb + kb * 32, DM);
      acc2 = __builtin_amdgcn_mfma_f32_16x16x32_bf16(af, bf, acc2, 0, 0, 0);
    }
  } else {      // Wsm @ V, K=256, A from LDS
    const ushort16* vtb = VTb + (size_t)(bh * HDIM + (w - 4) * 16) * TSTR;
#pragma unroll 2
    for (int kb = 0; kb < 8; ++kb) {
      bf16x8 af = *(const bf16x8*)&wsh[col][kb * 32 + ((lane >> 4) << 3)];
      bf16x8 bf = ldfrag(vtb + kb * 32, TSTR);
      acc2 = __builtin_amdgcn_mfma_f32_16x16x32_bf16(af, bf, acc2, 0, 0, 0);
    }
  }
  if (w < 4) {
#pragma unroll
    for (int r = 0; r < 4; ++r) fB[rb + r][w * 16 + col] = acc2[r];
  }
  __syncthreads();
  if (w >= 4) {
    int o = h * HDIM + (w - 4) * 16 + col;
    float bv = bv2[o];
#pragma unroll
    for (int r = 0; r < 4; ++r) {
      int ig = ib + rb + r;
      out[((size_t)(b * NTOK) + ig) * DM + o] = fB[rb + r][(w - 4) * 16 + col] + acc2[r] + bv;
    }
  }
}

extern "C" void kernel_launch(void* const* d_in, const int* in_sizes, int n_in,
                              void* d_out, int out_size, void* d_ws, size_t ws_size,
                              hipStream_t stream) {
  const float* x      = (const float*)d_in[0];
  const float* coords = (const float*)d_in[1];
  const float* Wqkv   = (const float*)d_in[2];
  const float* bqkv   = (const float*)d_in[3];
  const float* Wb1    = (const float*)d_in[4];
  const float* bb1    = (const float*)d_in[5];
  const float* Wb2    = (const float*)d_in[6];
  // d_in[7] = bb2: softmax-invariant, unused
  const float* Wv1    = (const float*)d_in[8];
  const float* bv1    = (const float*)d_in[9];
  const float* Wv2    = (const float*)d_in[10];
  const float* bv2    = (const float*)d_in[11];
  float* outp = (float*)d_out;
  float* ws = (float*)d_ws;

  const size_t SZ = (size_t)BATCH * NTOK * DM;           // 262144
  float* Svw = ws;
  float* DjT = ws + SZ;                                  // [bh][j], 4096 floats
  ushort16* SbW  = (ushort16*)(DjT + 4096);              // [bh][tok][PD]
  ushort16* Pbw  = SbW + (size_t)BATCH * NH * NTOK * PD;
  ushort16* PvT  = Pbw + (size_t)BATCH * NTOK * PD;      // [b][d][TSTR]
  ushort16* Pv2T = PvT + (size_t)BATCH * DM * TSTR;
  ushort16* Qb   = Pv2T + (size_t)BATCH * DM * TSTR;     // [bh][i][64]
  ushort16* Kb   = Qb + (size_t)BATCH * NH * NTOK * HDIM;
  ushort16* VTb  = Kb + (size_t)BATCH * NH * NTOK * HDIM;    // [bh][dp][TSTR]
  ushort16* xb   = VTb + (size_t)BATCH * NH * HDIM * TSTR;   // [row][DM]
  ushort16* Wqb  = xb + (size_t)BATCH * NTOK * DM;           // [n][DM]
  ushort16* Wv2b = Wqb + (size_t)3 * DM * DM;                // [o][DM]

  hipLaunchKernelGGL(stage0, dim3(768), dim3(256), 0, stream,
                     coords, Wb1, bb1, Wv1, bv1, Wb2, x, Wqkv, Wv2,
                     Svw, SbW, Pbw, PvT, Pv2T, DjT, xb, Wqb, Wv2b);
  hipLaunchKernelGGL(qkv_mfma, dim3(12, 32), dim3(128), 0, stream,
                     xb, Wqb, bqkv, Qb, Kb, VTb);
  hipLaunchKernelGGL(attn_fused2, dim3(16, BATCH * NH), dim3(512), 0, stream,
                     Qb, Kb, SbW, Pbw, DjT, PvT, Pv2T, Svw, Wv2b, VTb, bv2, outp);
}